// Round 1
// baseline (1649.092 us; speedup 1.0000x reference)
//
#include <hip/hip_runtime.h>
#include <math.h>

// FastGRNN fused recurrence.
// Design (v1): grid 128 blocks x 512 thr. lane = batch row (64 rows/block),
// 8 waves each own 16 hidden units (DHP=128 padded; pad rows of U1/cols of
// U2/WW/FC zeroed so padding is inert). H lives in registers. Weights are
// wave-uniform -> scalar (SGPR) loads. Per-step LDS traffic: rank-32 pd/d
// interchange + X tile only. 2 barriers/step.
// Precision: all fp32 (bf16/MFMA fails: 99-step error accumulation vs 2.75e-2
// abs threshold at |score|~468). U-path keeps reference association
// (H@U1 then @U2); input proj uses WW=W1@W2 precomputed (err ~1e-7).

#define TSTEPS 99
#define DIN    32
#define DH     100
#define DHP    128   // 8 waves * 16 units
#define UPT    16    // units per wave
#define RUP    32    // padded low-rank (real 25)
#define NW     8
#define ROWS   64
#define NCLS   6
#define XROW   3168  // T*DIN

// workspace float offsets
#define OFF_WW 0         // [32][128]  W1@W2, padded cols
#define OFF_U1 4096      // [128][32]  U1 padded (zeros outside [100][25])
#define OFF_U2 8192      // [32][128]  U2 padded (zeros outside [25][100])
#define OFF_FC 12288     // [128][8]   FC padded
#define OFF_EG 13312     // [128] exp(-bias_gate)
#define OFF_EU 13440     // [128] exp(-2*bias_update)
#define OFF_SZ 13568
#define OFF_SN 13569
#define WSF    13570

__global__ __launch_bounds__(256) void precomp(
    const float* __restrict__ W1, const float* __restrict__ W2,
    const float* __restrict__ U1, const float* __restrict__ U2,
    const float* __restrict__ bg, const float* __restrict__ bu,
    const float* __restrict__ zeta, const float* __restrict__ nu,
    const float* __restrict__ FC, float* __restrict__ ws)
{
    int idx = blockIdx.x * 256 + threadIdx.x;
    if (idx < 4096) {                       // WW[i][j] = sum_r W1[i][r]*W2[r][j]
        int j = idx & 127, i = idx >> 7;
        float v = 0.f;
        if (j < DH) {
            #pragma unroll
            for (int r = 0; r < 16; ++r) v = fmaf(W1[i*16 + r], W2[r*DH + j], v);
        }
        ws[OFF_WW + idx] = v;
    } else if (idx < 8192) {                // U1p[k][r]
        int q = idx - 4096; int r = q & 31, k = q >> 5;
        ws[OFF_U1 + q] = (k < DH && r < 25) ? U1[k*25 + r] : 0.f;
    } else if (idx < 12288) {               // U2p[r][j]
        int q = idx - 8192; int j = q & 127, r = q >> 7;
        ws[OFF_U2 + q] = (r < 25 && j < DH) ? U2[r*DH + j] : 0.f;
    } else if (idx < 13312) {               // FCp[k][c]
        int q = idx - 12288; int c = q & 7, k = q >> 3;
        ws[OFF_FC + q] = (k < DH && c < NCLS) ? FC[k*NCLS + c] : 0.f;
    } else if (idx < 13440) {
        int j = idx - 13312;
        ws[OFF_EG + j] = (j < DH) ? expf(-bg[j]) : 1.f;
    } else if (idx < 13568) {
        int j = idx - 13440;
        ws[OFF_EU + j] = (j < DH) ? expf(-2.f * bu[j]) : 1.f;
    } else if (idx == 13568) {
        ws[OFF_SZ] = 1.f / (1.f + expf(-zeta[0]));
    } else if (idx == 13569) {
        ws[OFF_SN] = 1.f / (1.f + expf(-nu[0]));
    }
}

__global__ __launch_bounds__(512, 2) void fastgrnn_main(
    const float* __restrict__ x, const float* __restrict__ ws,
    const float* __restrict__ FCbias, float* __restrict__ out)
{
    // stride pads chosen so float-index%32 spreads banks: 36 -> (4*row+4*q)%32,
    // 65 -> (i+row)%32.
    __shared__ float XT[DIN][ROWS + 1];                    // [32][65]
    __shared__ __align__(16) float pdL[NW][ROWS][RUP + 4]; // [8][64][36]
    __shared__ __align__(16) float dL[ROWS][RUP + 4];      // [64][36]

    const int tid = threadIdx.x;
    const int wu  = __builtin_amdgcn_readfirstlane(tid >> 6); // wave id, uniform
    const int row = tid & 63;                                  // lane = batch row
    const int blk = blockIdx.x;
    const long grow = (long)blk * ROWS + row;

    const float* __restrict__ U1w = ws + OFF_U1 + (wu * UPT) * RUP; // our 16 k-rows
    const float* __restrict__ WWw = ws + OFF_WW + wu * UPT;         // our 16 j-cols
    const float* __restrict__ U2w = ws + OFF_U2 + wu * UPT;
    const float* __restrict__ egp = ws + OFF_EG + wu * UPT;
    const float* __restrict__ eup = ws + OFF_EU + wu * UPT;
    const float sz = ws[OFF_SZ];
    const float sn = ws[OFF_SN];

    // X staging ids: 8 lanes per row, float4 each -> 64x32 tile
    const int srow  = tid >> 3;
    const int squad = (tid & 7) * 4;
    const float* __restrict__ xrow = x + ((long)blk * ROWS + srow) * XROW + squad;

    float H[UPT];
    #pragma unroll
    for (int u = 0; u < UPT; ++u) H[u] = 0.f;

    for (int t = 0; t < TSTEPS; ++t) {
        // 1) issue this step's X tile load early (consumed after bar2)
        const float4 xv = *(const float4*)(xrow + t * DIN);

        // 2) pd[r] = sum over OUR 16 k of H[k]*U1p[k][r]  (H in regs, U1 scalar)
        float pd[RUP];
        #pragma unroll
        for (int r = 0; r < RUP; ++r) pd[r] = 0.f;
        #pragma unroll 4
        for (int u = 0; u < UPT; ++u) {
            const float hu = H[u];
            const float* __restrict__ u1r = U1w + u * RUP;
            #pragma unroll
            for (int r = 0; r < RUP; ++r) pd[r] = fmaf(hu, u1r[r], pd[r]);
        }
        #pragma unroll
        for (int q = 0; q < RUP/4; ++q) {
            *(float4*)&pdL[wu][row][q*4] =
                make_float4(pd[q*4], pd[q*4+1], pd[q*4+2], pd[q*4+3]);
        }
        __syncthreads();  // bar1: pd visible

        // 3) reduce across waves: this wave owns r-quad = wu; also write XT
        {
            float4 a = *(const float4*)&pdL[0][row][wu*4];
            #pragma unroll
            for (int w2 = 1; w2 < NW; ++w2) {
                const float4 b = *(const float4*)&pdL[w2][row][wu*4];
                a.x += b.x; a.y += b.y; a.z += b.z; a.w += b.w;
            }
            *(float4*)&dL[row][wu*4] = a;
        }
        XT[squad+0][srow] = xv.x;
        XT[squad+1][srow] = xv.y;
        XT[squad+2][srow] = xv.z;
        XT[squad+3][srow] = xv.w;
        __syncthreads();  // bar2: d + XT visible

        // 4) c = X@WW + d@U2 for our 16 units
        float c2[UPT];
        #pragma unroll
        for (int u = 0; u < UPT; ++u) c2[u] = 0.f;

        #pragma unroll 4
        for (int i = 0; i < DIN; ++i) {
            const float xi = XT[i][row];
            const float* __restrict__ wwr = WWw + i * DHP;
            #pragma unroll
            for (int u = 0; u < UPT; ++u) c2[u] = fmaf(xi, wwr[u], c2[u]);
        }

        float dv[RUP];
        #pragma unroll
        for (int q = 0; q < RUP/4; ++q)
            *(float4*)&dv[q*4] = *(const float4*)&dL[row][q*4];
        #pragma unroll 5
        for (int r = 0; r < 25; ++r) {
            const float dr = dv[r];
            const float* __restrict__ u2r = U2w + r * DHP;
            #pragma unroll
            for (int u = 0; u < UPT; ++u) c2[u] = fmaf(dr, u2r[u], c2[u]);
        }

        // 5) gates: g = sigmoid(c+bg) = 1/(1+E*Eg), E = e^-c;
        //    h = tanh(c+bu) = (1-p)/(1+p), p = E^2*Eu (clamped to avoid inf/inf)
        #pragma unroll
        for (int u = 0; u < UPT; ++u) {
            const float cc = c2[u];
            const float E  = __expf(-cc);
            const float g  = __builtin_amdgcn_rcpf(fmaf(E, egp[u], 1.f));
            float p = E * E * eup[u];
            p = fminf(p, 1e30f);
            const float h = (1.f - p) * __builtin_amdgcn_rcpf(1.f + p);
            // H = g*H + (sz*(1-g) + sn*h)
            H[u] = fmaf(g, H[u], fmaf(sn, h, fmaf(-sz, g, sz)));
        }
    }

    // final: score = H@FC + bias; partial per wave, reduce via LDS
    float sc[NCLS];
    #pragma unroll
    for (int cix = 0; cix < NCLS; ++cix) sc[cix] = 0.f;
    const float* __restrict__ fcw = ws + OFF_FC + (wu * UPT) * 8;
    #pragma unroll
    for (int u = 0; u < UPT; ++u) {
        #pragma unroll
        for (int cix = 0; cix < NCLS; ++cix)
            sc[cix] = fmaf(H[u], fcw[u*8 + cix], sc[cix]);
    }
    __syncthreads();
    float* red = &pdL[0][0][0];  // reuse as [NW][ROWS][8]
    #pragma unroll
    for (int cix = 0; cix < NCLS; ++cix) red[(wu*ROWS + row)*8 + cix] = sc[cix];
    __syncthreads();
    if (wu == 0) {
        #pragma unroll
        for (int cix = 0; cix < NCLS; ++cix) {
            float a = red[row*8 + cix];
            #pragma unroll
            for (int w2 = 1; w2 < NW; ++w2) a += red[(w2*ROWS + row)*8 + cix];
            out[grow*NCLS + cix] = a + FCbias[cix];
        }
    }
}

extern "C" void kernel_launch(void* const* d_in, const int* in_sizes, int n_in,
                              void* d_out, int out_size, void* d_ws, size_t ws_size,
                              hipStream_t stream)
{
    const float* x    = (const float*)d_in[0];
    const float* W1   = (const float*)d_in[1];
    const float* W2   = (const float*)d_in[2];
    const float* U1   = (const float*)d_in[3];
    const float* U2   = (const float*)d_in[4];
    const float* bg   = (const float*)d_in[5];
    const float* bu   = (const float*)d_in[6];
    const float* zeta = (const float*)d_in[7];
    const float* nu   = (const float*)d_in[8];
    const float* FC   = (const float*)d_in[9];
    const float* FCb  = (const float*)d_in[10];
    float* ws  = (float*)d_ws;
    float* out = (float*)d_out;

    precomp<<<(WSF + 255) / 256, 256, 0, stream>>>(W1, W2, U1, U2, bg, bu,
                                                   zeta, nu, FC, ws);
    fastgrnn_main<<<128, 512, 0, stream>>>(x, ws, FCb, out);
}

// Round 2
// 1113.033 us; speedup vs baseline: 1.4816x; 1.4816x over previous
//
#include <hip/hip_runtime.h>
#include <math.h>

// FastGRNN fused recurrence — v2: lane = hidden unit, weights in VGPRs.
// Reassociation: c = X@WW + H@Ueff with WW=W1@W2 [32][100], Ueff=U1@U2
// [100][100] precomputed in fp32 (reassoc err ~1e-6/step; budget 2.75e-2,
// v1 measured 3e-5 with the WW fold alone).
// Block = 128 thr (2 waves) = 128 unit-lanes (100 real, pad cols zeroed),
// R=8 rows/block -> 1024 blocks. Per lane: Ueff column (100 VGPR) + WW
// column (32 VGPR) loaded ONCE before the t-loop. H in LDS [2][8][128]
// double-buffered: written lane-indexed (conflict-free), read as
// uniform-address float4 broadcasts (conflict-free). 1 barrier/step.
// x read at wave-uniform addresses -> scalar/broadcast loads.
// v1 post-mortem: 157KB LDS -> 1 block/CU, 2e8 bank-conflict cycles on the
// stride-36 interchange, per-step scalar weight refetch. All three removed.

#define TSTEPS 99
#define DIN    32
#define DH     100
#define DHP    128
#define R      8
#define NCLS   6
#define XROW   3168

// workspace float offsets
#define OFF_WW 0         // [32][128]   WW[i][j], cols >=100 zero
#define OFF_UE 4096      // [100][128]  Ueff[k][j], cols >=100 zero
#define OFF_EG 16896     // [128] exp(-bias_gate), pad 1
#define OFF_EU 17024     // [128] exp(-2*bias_update), pad 1
#define OFF_SZ 17152
#define OFF_SN 17153
#define WSF    17154

__global__ __launch_bounds__(256) void precomp(
    const float* __restrict__ W1, const float* __restrict__ W2,
    const float* __restrict__ U1, const float* __restrict__ U2,
    const float* __restrict__ bg, const float* __restrict__ bu,
    const float* __restrict__ zeta, const float* __restrict__ nu,
    float* __restrict__ ws)
{
    int idx = blockIdx.x * 256 + threadIdx.x;
    if (idx < 4096) {                        // WW[i][j]
        int j = idx & 127, i = idx >> 7;
        float v = 0.f;
        if (j < DH) {
            #pragma unroll
            for (int r = 0; r < 16; ++r) v = fmaf(W1[i*16 + r], W2[r*DH + j], v);
        }
        ws[OFF_WW + idx] = v;
    } else if (idx < 16896) {                // Ueff[k][j] = sum_r U1[k][r]U2[r][j]
        int q = idx - 4096; int j = q & 127, k = q >> 7;   // k in 0..99
        float v = 0.f;
        if (j < DH) {
            #pragma unroll
            for (int r = 0; r < 25; ++r) v = fmaf(U1[k*25 + r], U2[r*DH + j], v);
        }
        ws[OFF_UE + q] = v;
    } else if (idx < 17024) {
        int j = idx - 16896;
        ws[OFF_EG + j] = (j < DH) ? expf(-bg[j]) : 1.f;
    } else if (idx < 17152) {
        int j = idx - 17024;
        ws[OFF_EU + j] = (j < DH) ? expf(-2.f * bu[j]) : 1.f;
    } else if (idx == 17152) {
        ws[OFF_SZ] = 1.f / (1.f + expf(-zeta[0]));
    } else if (idx == 17153) {
        ws[OFF_SN] = 1.f / (1.f + expf(-nu[0]));
    }
}

__global__ __launch_bounds__(128, 2) void fastgrnn_main(
    const float* __restrict__ x, const float* __restrict__ ws,
    const float* __restrict__ FC, const float* __restrict__ FCbias,
    float* __restrict__ out)
{
    __shared__ __align__(16) float Hlds[2][R][DHP];   // 8 KB
    __shared__ float scoreL[R][2][NCLS];

    const int j   = threadIdx.x;         // unit lane 0..127 (real <100)
    const int w   = j >> 6;              // wave id 0/1
    const int row0 = blockIdx.x * R;

    // ---- one-time: weights into registers ----
    float ue[DH];
    #pragma unroll
    for (int k = 0; k < DH; ++k) ue[k] = ws[OFF_UE + k*DHP + j];
    float ww[DIN];
    #pragma unroll
    for (int i = 0; i < DIN; ++i) ww[i] = ws[OFF_WW + i*DHP + j];
    const float eg = ws[OFF_EG + j];
    const float eu = ws[OFF_EU + j];
    const float sz = ws[OFF_SZ];
    const float sn = ws[OFF_SN];
    float fc[NCLS];
    #pragma unroll
    for (int c = 0; c < NCLS; ++c) fc[c] = (j < DH) ? FC[j*NCLS + c] : 0.f;

    // zero H buffer 0
    #pragma unroll
    for (int r = 0; r < R; ++r) Hlds[0][r][j] = 0.f;
    __syncthreads();

    #pragma unroll 1
    for (int t = 0; t < TSTEPS; ++t) {
        const int cur = t & 1, nxt = cur ^ 1;
        #pragma unroll
        for (int r = 0; r < R; ++r) {
            // x quads: wave-uniform address -> scalar/broadcast loads
            const float* xr = x + (size_t)(row0 + r) * XROW + t * DIN;
            float4 xv[DIN/4];
            #pragma unroll
            for (int q = 0; q < DIN/4; ++q) xv[q] = ((const float4*)xr)[q];

            float a0 = 0.f, a1 = 0.f, a2 = 0.f, a3 = 0.f;
            #pragma unroll
            for (int q = 0; q < DH/4; ++q) {   // H broadcast quads
                const float4 h = *(const float4*)&Hlds[cur][r][4*q];
                a0 = fmaf(h.x, ue[4*q+0], a0);
                a1 = fmaf(h.y, ue[4*q+1], a1);
                a2 = fmaf(h.z, ue[4*q+2], a2);
                a3 = fmaf(h.w, ue[4*q+3], a3);
            }
            #pragma unroll
            for (int q = 0; q < DIN/4; ++q) {
                a0 = fmaf(xv[q].x, ww[4*q+0], a0);
                a1 = fmaf(xv[q].y, ww[4*q+1], a1);
                a2 = fmaf(xv[q].z, ww[4*q+2], a2);
                a3 = fmaf(xv[q].w, ww[4*q+3], a3);
            }
            const float cc = (a0 + a2) + (a1 + a3);

            const float Hold = Hlds[cur][r][j];
            const float E  = __expf(-cc);
            const float g  = __builtin_amdgcn_rcpf(fmaf(E, eg, 1.f));
            float p = E * E * eu;
            p = fminf(p, 1e30f);
            const float h  = (1.f - p) * __builtin_amdgcn_rcpf(1.f + p);
            Hlds[nxt][r][j] = fmaf(g, Hold, fmaf(sn, h, fmaf(-sz, g, sz)));
        }
        __syncthreads();
    }

    // ---- epilogue: score = H@FC + bias, reduce over unit-lanes ----
    const int fb = TSTEPS & 1;  // final buffer
    #pragma unroll
    for (int r = 0; r < R; ++r) {
        const float h = Hlds[fb][r][j];   // pad lanes: fc[]=0 so contribute 0
        float p[NCLS];
        #pragma unroll
        for (int c = 0; c < NCLS; ++c) p[c] = h * fc[c];
        #pragma unroll
        for (int off = 32; off >= 1; off >>= 1) {
            #pragma unroll
            for (int c = 0; c < NCLS; ++c) p[c] += __shfl_xor(p[c], off);
        }
        if ((j & 63) == 0) {
            #pragma unroll
            for (int c = 0; c < NCLS; ++c) scoreL[r][w][c] = p[c];
        }
    }
    __syncthreads();
    if (j < R * NCLS) {
        const int r = j / NCLS, c = j % NCLS;
        out[(size_t)(row0 + r) * NCLS + c] =
            scoreL[r][0][c] + scoreL[r][1][c] + FCbias[c];
    }
}

extern "C" void kernel_launch(void* const* d_in, const int* in_sizes, int n_in,
                              void* d_out, int out_size, void* d_ws, size_t ws_size,
                              hipStream_t stream)
{
    const float* x    = (const float*)d_in[0];
    const float* W1   = (const float*)d_in[1];
    const float* W2   = (const float*)d_in[2];
    const float* U1   = (const float*)d_in[3];
    const float* U2   = (const float*)d_in[4];
    const float* bg   = (const float*)d_in[5];
    const float* bu   = (const float*)d_in[6];
    const float* zeta = (const float*)d_in[7];
    const float* nu   = (const float*)d_in[8];
    const float* FC   = (const float*)d_in[9];
    const float* FCb  = (const float*)d_in[10];
    float* ws  = (float*)d_ws;
    float* out = (float*)d_out;

    precomp<<<(WSF + 255) / 256, 256, 0, stream>>>(W1, W2, U1, U2, bg, bu,
                                                   zeta, nu, ws);
    fastgrnn_main<<<(8192 / R), 128, 0, stream>>>(x, ws, FC, FCb, out);
}

// Round 3
// 907.410 us; speedup vs baseline: 1.8174x; 1.2266x over previous
//
#include <hip/hip_runtime.h>
#include <math.h>

// FastGRNN fused recurrence — v3: H in registers, readlane->SGPR broadcast.
// v2 post-mortem: LDS-return-BW-bound (25 b128 broadcasts/row/wave ~ 20k
// cyc/CU/step of the 25k wall; VALUBusy 40%). v3 removes H from LDS:
//   - block = 2 waves, R=8 rows. Lane L holds units (2L, 2L+1), L<50.
//   - wave w owns k in [50w,50w+50): U-path FMAs use H[k] fetched by
//     v_readlane (SGPR scalar operand) from the wave's OWN H registers.
//   - waves exchange only partial-c via LDS (1 b64 write + 1 b64 read per
//     row per wave, double-buffered by step parity, 1 barrier/step).
//   - both waves redundantly compute gates for all 100 units so H stays
//     wave-local (replaces ~300 cyc of LDS with ~80 cyc of VALU).
// Weights: Ueff=U1@U2 [100][100], WW=W1@W2 [32][100] precomputed fp32
// (v2 validated: absmax 3e-8). x loaded as wave-uniform float4 (64B/row/wave).

#define TSTEPS 99
#define DIN    32
#define DH     100
#define NCLS   6
#define XROW   3168
#define R      8

// workspace float offsets
#define OFF_UE 0         // [100][100] Ueff
#define OFF_WW 10000     // [32][100]  W1@W2
#define OFF_EG 13200     // [100] exp(-bias_gate)
#define OFF_EU 13300     // [100] exp(-2*bias_update)
#define OFF_SZ 13400
#define OFF_SN 13401
#define WSF    13402

__global__ __launch_bounds__(256) void precomp(
    const float* __restrict__ W1, const float* __restrict__ W2,
    const float* __restrict__ U1, const float* __restrict__ U2,
    const float* __restrict__ bg, const float* __restrict__ bu,
    const float* __restrict__ zeta, const float* __restrict__ nu,
    float* __restrict__ ws)
{
    int idx = blockIdx.x * 256 + threadIdx.x;
    if (idx < 10000) {                       // Ueff[k][j]
        int k = idx / 100, j = idx % 100;
        float v = 0.f;
        #pragma unroll
        for (int r = 0; r < 25; ++r) v = fmaf(U1[k*25 + r], U2[r*DH + j], v);
        ws[OFF_UE + idx] = v;
    } else if (idx < 13200) {                // WW[i][j]
        int q = idx - 10000; int i = q / 100, j = q % 100;
        float v = 0.f;
        #pragma unroll
        for (int r = 0; r < 16; ++r) v = fmaf(W1[i*16 + r], W2[r*DH + j], v);
        ws[OFF_WW + q] = v;
    } else if (idx < 13300) {
        ws[idx] = expf(-bg[idx - 13200]);
    } else if (idx < 13400) {
        ws[idx] = expf(-2.f * bu[idx - 13300]);
    } else if (idx == 13400) {
        ws[idx] = 1.f / (1.f + expf(-zeta[0]));
    } else if (idx == 13401) {
        ws[idx] = 1.f / (1.f + expf(-nu[0]));
    }
}

__device__ __forceinline__ float rdl(float v, int lane) {
    return __int_as_float(__builtin_amdgcn_readlane(__float_as_int(v), lane));
}

__global__ __launch_bounds__(128, 2) void fastgrnn_main(
    const float* __restrict__ x, const float* __restrict__ ws,
    const float* __restrict__ FC, const float* __restrict__ FCbias,
    float* __restrict__ out)
{
    __shared__ float2 pbuf[2][2][R][64];     // [parity][writer-wave][row][lane] = 16 KB
    const int tid = threadIdx.x;
    const int w   = __builtin_amdgcn_readfirstlane(tid >> 6);  // wave id, SGPR
    const int L   = tid & 63;
    const bool act = (L < 50);
    const int row0 = blockIdx.x * R;

    // ---- one-time: weight columns for units (2L, 2L+1), our k/i halves ----
    float uex[50], uey[50];
    #pragma unroll
    for (int kk = 0; kk < 50; ++kk) {
        float2 v = make_float2(0.f, 0.f);
        if (act) v = *(const float2*)&ws[OFF_UE + (50*w + kk)*DH + 2*L];
        uex[kk] = v.x; uey[kk] = v.y;
    }
    float wwx[16], wwy[16];
    #pragma unroll
    for (int ii = 0; ii < 16; ++ii) {
        float2 v = make_float2(0.f, 0.f);
        if (act) v = *(const float2*)&ws[OFF_WW + (16*w + ii)*DH + 2*L];
        wwx[ii] = v.x; wwy[ii] = v.y;
    }
    const float eg0 = act ? ws[OFF_EG + 2*L]     : 1.f;
    const float eg1 = act ? ws[OFF_EG + 2*L + 1] : 1.f;
    const float eu0 = act ? ws[OFF_EU + 2*L]     : 1.f;
    const float eu1 = act ? ws[OFF_EU + 2*L + 1] : 1.f;
    const float sz  = ws[OFF_SZ];
    const float sn  = ws[OFF_SN];

    float HA[R], HB[R];          // H[2L], H[2L+1] per row (identical in both waves)
    #pragma unroll
    for (int r = 0; r < R; ++r) { HA[r] = 0.f; HB[r] = 0.f; }
    float2 ownc[R];

    const float* __restrict__ xbase = x + (size_t)row0 * XROW + w * 16;

    for (int t = 0; t < TSTEPS; ++t) {
        const int par = t & 1;
        // ---- phase 1: partial c over our k-half (regs only), write b64 ----
        #pragma unroll
        for (int r = 0; r < R; ++r) {
            const float* xr = xbase + (size_t)r * XROW + t * DIN;
            const float4 xq0 = ((const float4*)xr)[0];
            const float4 xq1 = ((const float4*)xr)[1];
            const float4 xq2 = ((const float4*)xr)[2];
            const float4 xq3 = ((const float4*)xr)[3];

            float axa = 0.f, aya = 0.f, axb = 0.f, ayb = 0.f;
            #pragma unroll
            for (int m = 0; m < 25; ++m) {
                const int mm = 25*w + m;                 // SGPR lane index
                const float ha = rdl(HA[r], mm);         // H[2mm]
                const float hb = rdl(HB[r], mm);         // H[2mm+1]
                axa = fmaf(ha, uex[2*m],   axa);
                aya = fmaf(ha, uey[2*m],   aya);
                axb = fmaf(hb, uex[2*m+1], axb);
                ayb = fmaf(hb, uey[2*m+1], ayb);
            }
            const float xs[16] = { xq0.x, xq0.y, xq0.z, xq0.w,
                                   xq1.x, xq1.y, xq1.z, xq1.w,
                                   xq2.x, xq2.y, xq2.z, xq2.w,
                                   xq3.x, xq3.y, xq3.z, xq3.w };
            #pragma unroll
            for (int ii = 0; ii < 16; ++ii) {
                axa = fmaf(xs[ii], wwx[ii], axa);
                aya = fmaf(xs[ii], wwy[ii], aya);
            }
            float2 c; c.x = axa + axb; c.y = aya + ayb;
            ownc[r] = c;
            pbuf[par][w][r][L] = c;
        }
        __syncthreads();

        // ---- phase 2: combine halves, gates, update H (redundant per wave) ----
        #pragma unroll
        for (int r = 0; r < R; ++r) {
            const float2 oth = pbuf[par][w ^ 1][r][L];
            const float cx = ownc[r].x + oth.x;
            const float cy = ownc[r].y + oth.y;
            {
                const float E = __expf(-cx);
                const float g = __builtin_amdgcn_rcpf(fmaf(E, eg0, 1.f));
                float p = E * E * eu0;
                p = fminf(p, 1e30f);
                const float h = (1.f - p) * __builtin_amdgcn_rcpf(1.f + p);
                HA[r] = fmaf(g, HA[r], fmaf(sn, h, fmaf(-sz, g, sz)));
            }
            {
                const float E = __expf(-cy);
                const float g = __builtin_amdgcn_rcpf(fmaf(E, eg1, 1.f));
                float p = E * E * eu1;
                p = fminf(p, 1e30f);
                const float h = (1.f - p) * __builtin_amdgcn_rcpf(1.f + p);
                HB[r] = fmaf(g, HB[r], fmaf(sn, h, fmaf(-sz, g, sz)));
            }
        }
        // no 2nd barrier: next step writes pbuf[par^1]; pbuf[par] is rewritten
        // only at t+2, after t+1's barrier.
    }

    // ---- epilogue: score = H@FC + bias (wave 0 only; H identical) ----
    if (w == 0) {
        float fc0[NCLS], fc1[NCLS];
        #pragma unroll
        for (int c = 0; c < NCLS; ++c) {
            fc0[c] = act ? FC[(2*L)     * NCLS + c] : 0.f;
            fc1[c] = act ? FC[(2*L + 1) * NCLS + c] : 0.f;
        }
        #pragma unroll
        for (int r = 0; r < R; ++r) {
            float p[NCLS];
            #pragma unroll
            for (int c = 0; c < NCLS; ++c)
                p[c] = fmaf(HA[r], fc0[c], HB[r] * fc1[c]);
            #pragma unroll
            for (int off = 32; off >= 1; off >>= 1) {
                #pragma unroll
                for (int c = 0; c < NCLS; ++c) p[c] += __shfl_xor(p[c], off);
            }
            if (L == 0) {
                #pragma unroll
                for (int c = 0; c < NCLS; ++c)
                    out[(size_t)(row0 + r) * NCLS + c] = p[c] + FCbias[c];
            }
        }
    }
}

extern "C" void kernel_launch(void* const* d_in, const int* in_sizes, int n_in,
                              void* d_out, int out_size, void* d_ws, size_t ws_size,
                              hipStream_t stream)
{
    const float* x    = (const float*)d_in[0];
    const float* W1   = (const float*)d_in[1];
    const float* W2   = (const float*)d_in[2];
    const float* U1   = (const float*)d_in[3];
    const float* U2   = (const float*)d_in[4];
    const float* bg   = (const float*)d_in[5];
    const float* bu   = (const float*)d_in[6];
    const float* zeta = (const float*)d_in[7];
    const float* nu   = (const float*)d_in[8];
    const float* FC   = (const float*)d_in[9];
    const float* FCb  = (const float*)d_in[10];
    float* ws  = (float*)d_ws;
    float* out = (float*)d_out;

    precomp<<<(WSF + 255) / 256, 256, 0, stream>>>(W1, W2, U1, U2, bg, bu,
                                                   zeta, nu, ws);
    fastgrnn_main<<<8192 / R, 128, 0, stream>>>(x, ws, FC, FCb, out);
}